// Round 1
// baseline (9075.454 us; speedup 1.0000x reference)
//
#include <hip/hip_runtime.h>
#include <stdint.h>

#define B_  16
#define T_  2048
#define D_  512

typedef short v8s __attribute__((ext_vector_type(8)));
typedef float v4f __attribute__((ext_vector_type(4)));

// ws layout (bytes)
#define WT_OFF   0u            // 8 MB  bf16 weight fragments
#define H0R_OFF  8388608u      // 8 MB  tagged h ring, layer 0 (256 slots x 32KB)
#define H1R_OFF  16777216u     // 8 MB  tagged h ring, layer 1
#define XB_OFF   25165824u     // 32 MB x packed [t][d/8][b][8] bf16
#define WS_NEED  (XB_OFF + 33554432u)

#define RING_MASK 255
#define SLICE_W   8192         // 4B words per t-slice (512*16)

#define PSEL 0x07060302u       // v_perm: hi16(w0) | hi16(w1)<<16  (bf16 pair)
#define TSEL 0x05040100u       // v_perm: lo16(w0) | lo16(w1)<<16  (tag pair)

__device__ __forceinline__ short f2bf(float f) {
  unsigned u = __builtin_bit_cast(unsigned, f);
  u = (u + 0x7FFFu + ((u >> 16) & 1u)) >> 16;
  return (short)u;
}
__device__ __forceinline__ float sigmoid_fast(float z) { return 1.f / (1.f + __expf(-z)); }
__device__ __forceinline__ float tanh_fast(float z) {
  float e = __expf(2.f * z);
  return 1.f - 2.f / (e + 1.f);
}
__device__ __forceinline__ unsigned cohLoadU(const unsigned* p) {
  return __hip_atomic_load((unsigned*)p, __ATOMIC_RELAXED, __HIP_MEMORY_SCOPE_AGENT);
}
__device__ __forceinline__ unsigned long long cohLoadU2(const unsigned* p) {
  return __hip_atomic_load((unsigned long long*)p, __ATOMIC_RELAXED, __HIP_MEMORY_SCOPE_AGENT);
}
__device__ __forceinline__ void cohStoreU(unsigned* p, unsigned v) {
  __hip_atomic_store(p, v, __ATOMIC_RELAXED, __HIP_MEMORY_SCOPE_AGENT);
}
__device__ __forceinline__ unsigned vperm_(unsigned hi, unsigned lo, unsigned sel) {
  unsigned d;
  asm("v_perm_b32 %0, %1, %2, %3" : "=v"(d) : "v"(hi), "v"(lo), "s"(sel));
  return d;
}

// Load 16 MFMA A-fragments from a tagged slice. Fast path: plain (L2-shared)
// dwordx4 loads + inline tag verify. Slow path (stale/in-flight): agent-scope
// loads that bypass L1/L2, repeated until every word carries the step tag.
__device__ __forceinline__ void load_h_frags(const unsigned* p, unsigned tagrep, v8s afr[16]) {
  unsigned bad = 0;
#pragma unroll
  for (int kk = 0; kk < 16; ++kk) {
    uint4 u0 = *(const uint4*)(p + kk * 512);
    uint4 u1 = *(const uint4*)(p + kk * 512 + 4);
    unsigned d0 = vperm_(u0.y, u0.x, PSEL);
    unsigned d1 = vperm_(u0.w, u0.z, PSEL);
    unsigned d2 = vperm_(u1.y, u1.x, PSEL);
    unsigned d3 = vperm_(u1.w, u1.z, PSEL);
    bad |= vperm_(u0.y, u0.x, TSEL) ^ tagrep;
    bad |= vperm_(u0.w, u0.z, TSEL) ^ tagrep;
    bad |= vperm_(u1.y, u1.x, TSEL) ^ tagrep;
    bad |= vperm_(u1.w, u1.z, TSEL) ^ tagrep;
    uint4 pk; pk.x = d0; pk.y = d1; pk.z = d2; pk.w = d3;
    afr[kk] = __builtin_bit_cast(v8s, pk);
  }
  while (__ballot(bad != 0u)) {
    bad = 0;
#pragma unroll
    for (int kk = 0; kk < 16; ++kk) {
      const unsigned* q = p + kk * 512;
      unsigned long long w0 = cohLoadU2(q);
      unsigned long long w1 = cohLoadU2(q + 2);
      unsigned long long w2 = cohLoadU2(q + 4);
      unsigned long long w3 = cohLoadU2(q + 6);
      unsigned a0 = (unsigned)w0, a1 = (unsigned)(w0 >> 32);
      unsigned b0 = (unsigned)w1, b1 = (unsigned)(w1 >> 32);
      unsigned c0 = (unsigned)w2, c1 = (unsigned)(w2 >> 32);
      unsigned e0 = (unsigned)w3, e1 = (unsigned)(w3 >> 32);
      unsigned d0 = vperm_(a1, a0, PSEL);
      unsigned d1 = vperm_(b1, b0, PSEL);
      unsigned d2 = vperm_(c1, c0, PSEL);
      unsigned d3 = vperm_(e1, e0, PSEL);
      bad |= vperm_(a1, a0, TSEL) ^ tagrep;
      bad |= vperm_(b1, b0, TSEL) ^ tagrep;
      bad |= vperm_(c1, c0, TSEL) ^ tagrep;
      bad |= vperm_(e1, e0, TSEL) ^ tagrep;
      uint4 pk; pk.x = d0; pk.y = d1; pk.z = d2; pk.w = d3;
      afr[kk] = __builtin_bit_cast(v8s, pk);
    }
  }
}

// Wx/Wh fp32 [L][512][2048] -> bf16 MFMA B-fragment order (unchanged, validated)
// + zero the tagged h rings (16MB = exactly 4194304 words = grid size).
__global__ void prep_weights(const float* __restrict__ Wx, const float* __restrict__ Wh,
                             short* __restrict__ wT, unsigned* __restrict__ rings) {
  int tid = blockIdx.x * 256 + threadIdx.x;            // [0, 2^22)
  rings[tid] = 0u;
  int l   = tid >> 21;
  int mat = (tid >> 20) & 1;
  int rem = tid & ((1 << 20) - 1);
  int k   = rem >> 11;
  int col = rem & 2047;
  const float* src = mat ? Wh : Wx;
  float v = src[(l << 20) + (k << 11) + col];
  int q = col >> 9, r9 = col & 511, g = r9 >> 3, jj = r9 & 7;
  int c = q * 8 + jj, ntile = c >> 4, n = c & 15;
  int kap = k >> 5, k5 = k & 31, quad = k5 >> 3, j = k5 & 7;
  int lane = quad * 16 + n;
  int dst = ((((l * 2 + mat) * 64 + g) * 2 + ntile) * 16 + kap) * 512 + lane * 8 + j;
  wT[dst] = f2bf(v);
}

// x [b][t][d] fp32 -> packed xP[t][d/8][b][d%8] bf16 (A-fragment-native layout)
__global__ void prep_x(const float* __restrict__ x, short* __restrict__ xP) {
  int tid = blockIdx.x * 256 + threadIdx.x;            // [0, 2^24)
  int b = tid >> 20, r = tid & ((1 << 20) - 1), t = r >> 9, d = r & 511;
  xP[(size_t)t * 8192 + (d >> 3) * 128 + b * 8 + (d & 7)] = f2bf(x[tid]);
}

__device__ __forceinline__ void mfma16(const v8s* afr, const short* wbase, v4f& accE, v4f& accO) {
#pragma unroll
  for (int kk = 0; kk < 16; ++kk) {
    v4f& aR = (kk & 1) ? accO : accE;
    aR = __builtin_amdgcn_mfma_f32_16x16x32_bf16(afr[kk], *(const v8s*)(wbase + kk * 512), aR, 0, 0, 0);
  }
}

__global__ __launch_bounds__(256, 1) void lstm_persist(
    const float* __restrict__ x, const short* __restrict__ xP,
    const short* __restrict__ wT, const float* __restrict__ bias,
    unsigned* h0r, unsigned* h1r, float* __restrict__ out) {
  const int wg   = blockIdx.x;
  const int l    = wg >> 6;       // layer 0 or 1
  const int g    = wg & 63;       // column group (8 h-cols)
  const int tid  = threadIdx.x;
  const int wave = tid >> 6;
  const int lane = tid & 63;
  const int mat  = wave >> 1;     // 0 = input kernel, 1 = recurrent
  const int ntile = wave & 1;
  const int n15  = lane & 15;
  const int quad = lane >> 4;

  __shared__ float LDSG[2][16][36];
  __shared__ short WLDS[4][16][512];  // 64 KB weight fragments

  unsigned* hOwnR = l ? h1r : h0r;

  // stage loop-invariant B fragments -> LDS (once)
  {
    const short* wb = wT + (size_t)((((l * 2 + mat) * 64 + g) * 2 + ntile) * 16) * 512;
#pragma unroll
    for (int kk = 0; kk < 16; ++kk)
      *(v8s*)&WLDS[wave][kk][lane * 8] = *(const v8s*)(wb + kk * 512 + lane * 8);
  }
  __syncthreads();

  // epilogue mapping: one h element per lane across waves 0,1
  const int eIdx = wave * 64 + lane;   // [0,128) for waves 0,1
  const int bb   = eIdx >> 3;          // batch row
  const int ej   = eIdx & 7;           // col within group
  float bq[4] = {0.f, 0.f, 0.f, 0.f};
  if (wave < 2) {
#pragma unroll
    for (int q = 0; q < 4; ++q) bq[q] = bias[l * 2048 + q * 512 + g * 8 + ej];
  }
  float cst = 0.f;

  const int aOffW = quad * 128 + n15 * 8;   // A-fragment word offset in a slice
  const short* wbase = &WLDS[wave][0][lane * 8];

  for (int t = 0; t < T_; ++t) {
    const int slotP = (t - 1) & RING_MASK;
    const int slotC = t & RING_MASK;
    const unsigned tagP = (unsigned)t;        // tag carried by slice t-1
    const unsigned tagC = (unsigned)(t + 1);  // tag carried by slice t

    // residual x prefetch (hides HBM latency under the poll + MFMA)
    float xv = 0.f;
    if (l == 1 && wave < 2)
      xv = x[(size_t)bb * (T_ * D_) + (size_t)t * D_ + g * 8 + ej];

    // ---------- wave0: sentinel poll (one word per producer half-block) ----------
    if (wave == 0 && (l == 1 || t > 0)) {
      const unsigned* a0p = h0r + (l ? slotC : slotP) * SLICE_W + lane * 128;
      const unsigned  expA = l ? tagC : tagP;
      const bool dual = (l == 1 && t > 0);
      const unsigned* b0p = h1r + slotP * SLICE_W + lane * 128;
      for (;;) {
        unsigned a = cohLoadU(a0p), b = cohLoadU(a0p + 64);
        bool ok = ((a & 0xFFFFu) == expA) && ((b & 0xFFFFu) == expA);
        if (dual) {
          unsigned c = cohLoadU(b0p), d = cohLoadU(b0p + 64);
          ok = ok && ((c & 0xFFFFu) == tagP) && ((d & 0xFFFFu) == tagP);
        }
        if (__ballot(ok) == ~0ull) break;
        __builtin_amdgcn_s_sleep(1);
      }
    }
    __syncthreads();

    // ---------- MFMA: 16-col tile, 2-accumulator interleave ----------
    v4f accE = {0.f, 0.f, 0.f, 0.f};
    v4f accO = {0.f, 0.f, 0.f, 0.f};
    if (mat == 0) {
      if (l == 0) {
        const short* p = xP + (size_t)t * 8192 + aOffW;
        v8s afr[16];
#pragma unroll
        for (int kk = 0; kk < 16; ++kk) afr[kk] = *(const v8s*)(p + kk * 512);
        mfma16(afr, wbase, accE, accO);
      } else {
        v8s afr[16];
        load_h_frags(h0r + slotC * SLICE_W + aOffW, tagC | (tagC << 16), afr);
        mfma16(afr, wbase, accE, accO);
      }
    } else if (t > 0) {
      v8s afr[16];
      load_h_frags(hOwnR + slotP * SLICE_W + aOffW, tagP | (tagP << 16), afr);
      mfma16(afr, wbase, accE, accO);
    }
    {
      v4f acc = accE + accO;
      const int rb = quad * 4;
#pragma unroll
      for (int r = 0; r < 4; ++r)
        LDSG[mat][rb + r][ntile * 16 + n15] = acc[r];
    }
    __syncthreads();

    // ---------- epilogue on waves 0+1: gates -> (c,h), fire-and-forget publish ----------
    if (wave < 2) {
      float s0 = LDSG[0][bb][0  + ej] + LDSG[1][bb][0  + ej] + bq[0];
      float s1 = LDSG[0][bb][8  + ej] + LDSG[1][bb][8  + ej] + bq[1];
      float s2 = LDSG[0][bb][16 + ej] + LDSG[1][bb][16 + ej] + bq[2];
      float s3 = LDSG[0][bb][24 + ej] + LDSG[1][bb][24 + ej] + bq[3];
      float iv = sigmoid_fast(s0), fv = sigmoid_fast(s1);
      float gv = tanh_fast(s2),    ov = sigmoid_fast(s3);
      cst = fv * cst + iv * gv;
      float hv = ov * tanh_fast(cst);
      unsigned word = ((unsigned)(unsigned short)f2bf(hv) << 16) | tagC;
      // self-validating word: no waitcnt drain, no flag store
      cohStoreU(hOwnR + slotC * SLICE_W + g * 128 + eIdx, word);
      if (l == 1) {
        size_t xi = (size_t)bb * (T_ * D_) + (size_t)t * D_ + g * 8 + ej;
        out[xi] = hv + xv;
      }
    }
  }
}

extern "C" void kernel_launch(void* const* d_in, const int* in_sizes, int n_in,
                              void* d_out, int out_size, void* d_ws, size_t ws_size,
                              hipStream_t stream) {
  const float* x    = (const float*)d_in[0];
  const float* Wx   = (const float*)d_in[1];
  const float* Wh   = (const float*)d_in[2];
  const float* bias = (const float*)d_in[3];
  float* out = (float*)d_out;

  char* ws      = (char*)d_ws;
  short* wT     = (short*)(ws + WT_OFF);
  unsigned* h0r = (unsigned*)(ws + H0R_OFF);
  unsigned* h1r = (unsigned*)(ws + H1R_OFF);
  short* xP     = (short*)(ws + XB_OFF);

  hipLaunchKernelGGL(prep_weights, dim3(16384), dim3(256), 0, stream, Wx, Wh, wT, h0r);
  hipLaunchKernelGGL(prep_x, dim3(65536), dim3(256), 0, stream, x, xP);
  hipLaunchKernelGGL(lstm_persist, dim3(128), dim3(256), 0, stream,
                     x, xP, wT, bias, h0r, h1r, out);
}

// Round 2
// 5759.433 us; speedup vs baseline: 1.5758x; 1.5758x over previous
//
#include <hip/hip_runtime.h>
#include <stdint.h>

#define B_  16
#define T_  2048
#define D_  512

typedef short v8s __attribute__((ext_vector_type(8)));
typedef float v4f __attribute__((ext_vector_type(4)));

// ws layout (bytes)
#define WT_OFF   0u            // 8 MB  bf16 weight fragments
#define H0_OFF   8388608u      // 32 MB linear h0, bf16 packed [t][d/8][b][8], sentinel-filled
#define H1_OFF   41943040u     // 32 MB linear h1
#define XB_OFF   75497472u     // 32 MB x packed [t][d/8][b][8] bf16
#define WS_NEED  (XB_OFF + 33554432u)

#define SENT 0xFFFFFFFFu       // two bf16 NaNs; |h|<=1.0 -> valid words never match

__device__ __forceinline__ short f2bf(float f) {
  unsigned u = __builtin_bit_cast(unsigned, f);
  u = (u + 0x7FFFu + ((u >> 16) & 1u)) >> 16;
  return (short)u;
}
__device__ __forceinline__ float sigmoid_fast(float z) { return 1.f / (1.f + __expf(-z)); }
__device__ __forceinline__ float tanh_fast(float z) {
  float e = __expf(2.f * z);
  return 1.f - 2.f / (e + 1.f);
}
__device__ __forceinline__ unsigned long long cohLoadU2(const unsigned* p) {
  return __hip_atomic_load((unsigned long long*)p, __ATOMIC_RELAXED, __HIP_MEMORY_SCOPE_AGENT);
}
__device__ __forceinline__ void cohStoreU(unsigned* p, unsigned v) {
  __hip_atomic_store(p, v, __ATOMIC_RELAXED, __HIP_MEMORY_SCOPE_AGENT);
}

// Wx/Wh fp32 [L][512][2048] -> bf16 MFMA B-fragment order (unchanged, validated)
__global__ void prep_weights(const float* __restrict__ Wx, const float* __restrict__ Wh,
                             short* __restrict__ wT) {
  int tid = blockIdx.x * 256 + threadIdx.x;            // [0, 2^22)
  int l   = tid >> 21;
  int mat = (tid >> 20) & 1;
  int rem = tid & ((1 << 20) - 1);
  int k   = rem >> 11;
  int col = rem & 2047;
  const float* src = mat ? Wh : Wx;
  float v = src[(l << 20) + (k << 11) + col];
  int q = col >> 9, r9 = col & 511, g = r9 >> 3, jj = r9 & 7;
  int c = q * 8 + jj, ntile = c >> 4, n = c & 15;
  int kap = k >> 5, k5 = k & 31, quad = k5 >> 3, j = k5 & 7;
  int lane = quad * 16 + n;
  int dst = ((((l * 2 + mat) * 64 + g) * 2 + ntile) * 16 + kap) * 512 + lane * 8 + j;
  wT[dst] = f2bf(v);
}

// x [b][t][d] fp32 -> packed xP[t][d/8][b][d%8] bf16, AND sentinel-fill both h
// buffers (h0+h1 = 16M u32 words == grid size 2^24, contiguous at H0_OFF).
__global__ void prep_x(const float* __restrict__ x, short* __restrict__ xP,
                       unsigned* __restrict__ hwords) {
  int tid = blockIdx.x * 256 + threadIdx.x;            // [0, 2^24)
  hwords[tid] = SENT;
  int b = tid >> 20, r = tid & ((1 << 20) - 1), t = r >> 9, d = r & 511;
  xP[(size_t)t * 8192 + (d >> 3) * 128 + b * 8 + (d & 7)] = f2bf(x[tid]);
}

__device__ __forceinline__ void mfma16(const v8s* afr, const v8s* wfr, v4f& accE, v4f& accO) {
#pragma unroll
  for (int kk = 0; kk < 16; ++kk) {
    v4f& aR = (kk & 1) ? accO : accE;
    aR = __builtin_amdgcn_mfma_f32_16x16x32_bf16(afr[kk], wfr[kk], aR, 0, 0, 0);
  }
}

// 16 A-fragments via agent-scope (IF$) loads; returns running max over all
// u32 words.  mx == SENT  <=>  at least one word still unwritten.
__device__ __forceinline__ unsigned coh_load16(const short* p, v8s afr[16]) {
  unsigned mx = 0;
#pragma unroll
  for (int kk = 0; kk < 16; ++kk) {
    const unsigned* q = (const unsigned*)(p + kk * 512);
    unsigned long long w0 = cohLoadU2(q);
    unsigned long long w1 = cohLoadU2(q + 2);
    unsigned a = (unsigned)w0, b = (unsigned)(w0 >> 32);
    unsigned c = (unsigned)w1, d = (unsigned)(w1 >> 32);
    mx = a > mx ? a : mx;
    mx = b > mx ? b : mx;
    mx = c > mx ? c : mx;
    mx = d > mx ? d : mx;
    uint4 pk; pk.x = a; pk.y = b; pk.z = c; pk.w = d;
    afr[kk] = __builtin_bit_cast(v8s, pk);
  }
  return mx;
}

__global__ __launch_bounds__(256, 1) void lstm_persist(
    const float* __restrict__ x, const short* __restrict__ xP,
    const short* __restrict__ wT, const float* __restrict__ bias,
    short* h0, short* h1, float* __restrict__ out) {
  const int wg   = blockIdx.x;
  const int l    = wg >> 6;       // layer 0 or 1
  const int g    = wg & 63;       // column group (8 h-cols)
  const int tid  = threadIdx.x;
  const int wave = tid >> 6;
  const int lane = tid & 63;
  const int mat  = wave >> 1;     // 0 = input kernel, 1 = recurrent
  const int ntile = wave & 1;
  const int n15  = lane & 15;
  const int quad = lane >> 4;

  __shared__ float LDSG[2][16][36];

  short* hOwn = l ? h1 : h0;

  // loop-invariant B fragments -> VGPRs (64 VGPR; removes ds_read from chain)
  v8s wfr[16];
  {
    const short* wb = wT + (size_t)((((l * 2 + mat) * 64 + g) * 2 + ntile) * 16) * 512 + lane * 8;
#pragma unroll
    for (int kk = 0; kk < 16; ++kk) wfr[kk] = *(const v8s*)(wb + kk * 512);
  }

  // wave0 epilogue state: lane -> (batch bb, col pair jp): cols g*8+2jp, +1
  const int bb = lane >> 2, jp = lane & 3;
  float bq[4][2];
#pragma unroll
  for (int q = 0; q < 4; ++q) {
    bq[q][0] = bias[l * 2048 + q * 512 + g * 8 + 2 * jp];
    bq[q][1] = bias[l * 2048 + q * 512 + g * 8 + 2 * jp + 1];
  }
  float c0 = 0.f, c1 = 0.f;

  const int aOff = quad * 128 + n15 * 8;   // A-fragment short offset in a t-slice

  for (int t = 0; t < T_; ++t) {
    // residual x prefetch (wave0/l1): issue early, consume in epilogue
    float2 xv;
    size_t xi = 0;
    if (l == 1 && wave == 0) {
      xi = (size_t)bb * (T_ * D_) + (size_t)t * D_ + g * 8 + 2 * jp;
      xv = *(const float2*)(x + xi);
    }

    v4f accE = {0.f, 0.f, 0.f, 0.f};
    v4f accO = {0.f, 0.f, 0.f, 0.f};
    const short* hp = nullptr;
    if (mat == 0) {
      if (l == 0) {
        const short* p = xP + (size_t)t * 8192 + aOff;   // static input, plain loads
        v8s afr[16];
#pragma unroll
        for (int kk = 0; kk < 16; ++kk) afr[kk] = *(const v8s*)(p + kk * 512);
        mfma16(afr, wfr, accE, accO);
      } else {
        hp = h0 + (size_t)t * 8192 + aOff;               // layer-0 output, step t
      }
    } else if (t > 0) {
      hp = hOwn + (size_t)(t - 1) * 8192 + aOff;         // own recurrence, step t-1
    }

    if (hp) {
      v8s afr[16];
      unsigned mx = coh_load16(hp, afr);
      mfma16(afr, wfr, accE, accO);                      // speculative; verify overlaps
      if (__ballot(mx == SENT) != 0) {                   // slow path: data not yet landed
        do {
          __builtin_amdgcn_s_sleep(1);
          mx = coh_load16(hp, afr);
        } while (__ballot(mx == SENT) != 0);
        accE = (v4f){0.f, 0.f, 0.f, 0.f};
        accO = (v4f){0.f, 0.f, 0.f, 0.f};
        mfma16(afr, wfr, accE, accO);
      }
    }

    {
      v4f acc = accE + accO;
      const int rb = quad * 4;
#pragma unroll
      for (int r = 0; r < 4; ++r)
        LDSG[mat][rb + r][ntile * 16 + n15] = acc[r];
    }
    __syncthreads();

    // ---------- wave0-only epilogue: gates -> (c,h), fire-and-forget publish ----------
    if (wave == 0) {
      float2 s[4];
#pragma unroll
      for (int q = 0; q < 4; ++q) {
        float2 a0 = *(const float2*)&LDSG[0][bb][q * 8 + 2 * jp];
        float2 a1 = *(const float2*)&LDSG[1][bb][q * 8 + 2 * jp];
        s[q].x = a0.x + a1.x + bq[q][0];
        s[q].y = a0.y + a1.y + bq[q][1];
      }
      float i0 = sigmoid_fast(s[0].x), i1 = sigmoid_fast(s[0].y);
      float f0 = sigmoid_fast(s[1].x), f1 = sigmoid_fast(s[1].y);
      float g0 = tanh_fast(s[2].x),    g1 = tanh_fast(s[2].y);
      float o0 = sigmoid_fast(s[3].x), o1 = sigmoid_fast(s[3].y);
      c0 = f0 * c0 + i0 * g0;
      c1 = f1 * c1 + i1 * g1;
      float h0v = o0 * tanh_fast(c0);
      float h1v = o1 * tanh_fast(c1);
      unsigned pack = (unsigned)(unsigned short)f2bf(h0v) |
                      ((unsigned)(unsigned short)f2bf(h1v) << 16);
      // |h|<=1 so pack never equals SENT in either half; single atomic u32:
      // no waitcnt drain, no flag — consumers self-verify.
      cohStoreU((unsigned*)hOwn + (size_t)t * 4096 + g * 64 + bb * 4 + jp, pack);
      if (l == 1) {
        float2 ov; ov.x = h0v + xv.x; ov.y = h1v + xv.y;
        *(float2*)(out + xi) = ov;
      }
    }
    __syncthreads();   // LDSG reuse fence for next iteration
  }
}

extern "C" void kernel_launch(void* const* d_in, const int* in_sizes, int n_in,
                              void* d_out, int out_size, void* d_ws, size_t ws_size,
                              hipStream_t stream) {
  const float* x    = (const float*)d_in[0];
  const float* Wx   = (const float*)d_in[1];
  const float* Wh   = (const float*)d_in[2];
  const float* bias = (const float*)d_in[3];
  float* out = (float*)d_out;

  char* ws   = (char*)d_ws;
  short* wT  = (short*)(ws + WT_OFF);
  short* h0  = (short*)(ws + H0_OFF);
  short* h1  = (short*)(ws + H1_OFF);
  short* xP  = (short*)(ws + XB_OFF);
  unsigned* hwords = (unsigned*)(ws + H0_OFF);   // h0+h1 contiguous, 2^24 words

  hipLaunchKernelGGL(prep_weights, dim3(16384), dim3(256), 0, stream, Wx, Wh, wT);
  hipLaunchKernelGGL(prep_x, dim3(65536), dim3(256), 0, stream, x, xP, hwords);
  hipLaunchKernelGGL(lstm_persist, dim3(128), dim3(256), 0, stream,
                     x, xP, wT, bias, h0, h1, out);
}

// Round 4
// 5092.785 us; speedup vs baseline: 1.7820x; 1.1309x over previous
//
#include <hip/hip_runtime.h>
#include <stdint.h>

#define B_  16
#define T_  2048
#define D_  512

typedef short v8s __attribute__((ext_vector_type(8)));
typedef float v4f __attribute__((ext_vector_type(4)));

// ws layout (bytes)
#define WT_OFF   0u            // 8 MB  bf16 weight fragments
#define H0_OFF   8388608u      // 32 MB linear h0, bf16 packed [t][d/8][b][8], sentinel-filled
#define H1_OFF   41943040u     // 32 MB linear h1
#define XB_OFF   75497472u     // 32 MB x packed [t][d/8][b][8] bf16
#define WS_NEED  (XB_OFF + 33554432u)

#define SENT 0xFFFFFFFFu       // two bf16 NaNs; |h|<=1.0 -> valid words never match

__device__ __forceinline__ short f2bf(float f) {
  unsigned u = __builtin_bit_cast(unsigned, f);
  u = (u + 0x7FFFu + ((u >> 16) & 1u)) >> 16;
  return (short)u;
}
__device__ __forceinline__ float sigmoid_fast(float z) { return 1.f / (1.f + __expf(-z)); }
__device__ __forceinline__ float tanh_fast(float z) {
  float e = __expf(2.f * z);
  return 1.f - 2.f / (e + 1.f);
}
__device__ __forceinline__ unsigned long long cohLoadU2(const unsigned* p) {
  return __hip_atomic_load((unsigned long long*)p, __ATOMIC_RELAXED, __HIP_MEMORY_SCOPE_AGENT);
}
__device__ __forceinline__ void cohStoreU(unsigned* p, unsigned v) {
  __hip_atomic_store(p, v, __ATOMIC_RELAXED, __HIP_MEMORY_SCOPE_AGENT);
}

// Wx/Wh fp32 [L][512][2048] -> bf16 MFMA B-fragment order (unchanged, validated)
__global__ void prep_weights(const float* __restrict__ Wx, const float* __restrict__ Wh,
                             short* __restrict__ wT) {
  int tid = blockIdx.x * 256 + threadIdx.x;            // [0, 2^22)
  int l   = tid >> 21;
  int mat = (tid >> 20) & 1;
  int rem = tid & ((1 << 20) - 1);
  int k   = rem >> 11;
  int col = rem & 2047;
  const float* src = mat ? Wh : Wx;
  float v = src[(l << 20) + (k << 11) + col];
  int q = col >> 9, r9 = col & 511, g = r9 >> 3, jj = r9 & 7;
  int c = q * 8 + jj, ntile = c >> 4, n = c & 15;
  int kap = k >> 5, k5 = k & 31, quad = k5 >> 3, j = k5 & 7;
  int lane = quad * 16 + n;
  int dst = ((((l * 2 + mat) * 64 + g) * 2 + ntile) * 16 + kap) * 512 + lane * 8 + j;
  wT[dst] = f2bf(v);
}

// x [b][t][d] fp32 -> packed xP[t][d/8][b][d%8] bf16, AND sentinel-fill both h
// buffers (h0+h1 = 16M u32 words == grid size 2^24, contiguous at H0_OFF).
__global__ void prep_x(const float* __restrict__ x, short* __restrict__ xP,
                       unsigned* __restrict__ hwords) {
  int tid = blockIdx.x * 256 + threadIdx.x;            // [0, 2^24)
  hwords[tid] = SENT;
  int b = tid >> 20, r = tid & ((1 << 20) - 1), t = r >> 9, d = r & 511;
  xP[(size_t)t * 8192 + (d >> 3) * 128 + b * 8 + (d & 7)] = f2bf(x[tid]);
}

// 8 half-slice A-fragments via agent-scope (IF$) loads; returns running max.
// mx == SENT  <=>  at least one word still unwritten.
__device__ __forceinline__ unsigned coh_load8(const short* p, v8s afr[8]) {
  unsigned mx = 0;
#pragma unroll
  for (int kk = 0; kk < 8; ++kk) {
    const unsigned* q = (const unsigned*)(p + kk * 512);
    unsigned long long w0 = cohLoadU2(q);
    unsigned long long w1 = cohLoadU2(q + 2);
    unsigned a = (unsigned)w0, b = (unsigned)(w0 >> 32);
    unsigned c = (unsigned)w1, d = (unsigned)(w1 >> 32);
    mx = a > mx ? a : mx;
    mx = b > mx ? b : mx;
    mx = c > mx ? c : mx;
    mx = d > mx ? d : mx;
    uint4 pk; pk.x = a; pk.y = b; pk.z = c; pk.w = d;
    afr[kk] = __builtin_bit_cast(v8s, pk);
  }
  return mx;
}

// 32 MFMAs: 8 K-fragments x 4 n-tiles, 4 independent accumulator chains
__device__ __forceinline__ void mfma32(const v8s afr[8], const v8s wfr[4][8], v4f acc[4]) {
#pragma unroll
  for (int kk = 0; kk < 8; ++kk) {
#pragma unroll
    for (int nt = 0; nt < 4; ++nt)
      acc[nt] = __builtin_amdgcn_mfma_f32_16x16x32_bf16(afr[kk], wfr[nt][kk], acc[nt], 0, 0, 0);
  }
}

__global__ __launch_bounds__(256, 1) void lstm_persist(
    const float* __restrict__ x, const short* __restrict__ xP,
    const short* __restrict__ wT, const float* __restrict__ bias,
    short* h0, short* h1, float* __restrict__ out) {
  const int wg   = blockIdx.x;
  const int l    = wg >> 5;       // layer 0 or 1
  const int g    = wg & 31;       // column group (16 h-cols)
  const int tid  = threadIdx.x;
  const int wave = tid >> 6;
  const int lane = tid & 63;
  const int m    = wave >> 1;     // 0 = input kernel, 1 = recurrent
  const int kh   = wave & 1;      // K-half this wave covers: [kh*256, kh*256+256)
  const int n15  = lane & 15;
  const int quad = lane >> 4;

  // gate partials: [buf][wave][batch row][4 ntiles x 16 + pad]
  __shared__ float LDSG[2][4][16][68];

  short* hOwn = l ? h1 : h0;

  // loop-invariant B fragments -> VGPRs: 4 n-tiles x 8 K-frags (128 VGPR)
  v8s wfr[4][8];
#pragma unroll
  for (int nt = 0; nt < 4; ++nt) {
    const int gOld = 2 * g + (nt >> 1);
    const int nt2  = nt & 1;
    const short* wb = wT + (size_t)((((l * 2 + m) * 64 + gOld) * 2 + nt2) * 16 + kh * 8) * 512 + lane * 8;
#pragma unroll
    for (int kk = 0; kk < 8; ++kk) wfr[nt][kk] = *(const v8s*)(wb + kk * 512);
  }

  // epilogue state (waves 0,1): eIdx -> (batch bb, col-pair jp): cols g*16+2jp, +1
  const int eIdx = wave * 64 + lane;   // [0,128)
  const int bb = eIdx >> 3, jp = eIdx & 7;
  const int hi = jp >> 2;              // which old 8-col half
  const int jj = 2 * (jp & 3);         // even col within the 8
  float bq[4][2];
#pragma unroll
  for (int q = 0; q < 4; ++q) {
    bq[q][0] = bias[l * 2048 + q * 512 + g * 16 + 2 * jp];
    bq[q][1] = bias[l * 2048 + q * 512 + g * 16 + 2 * jp + 1];
  }
  float c0 = 0.f, c1 = 0.f;

  const int aOff = kh * 4096 + quad * 128 + n15 * 8;  // half-slice A offset (shorts)

  for (int t = 0; t < T_; ++t) {
    const int buf = t & 1;

    // residual x prefetch (waves 0,1 / l1): issue early, consume in epilogue
    float2 xv;
    size_t xi = 0;
    if (l == 1 && wave < 2) {
      xi = (size_t)bb * (T_ * D_) + (size_t)t * D_ + g * 16 + 2 * jp;
      xv = *(const float2*)(x + xi);
    }

    v4f acc[4];
#pragma unroll
    for (int nt = 0; nt < 4; ++nt) acc[nt] = (v4f){0.f, 0.f, 0.f, 0.f};

    const short* hp = nullptr;
    if (m == 0) {
      if (l == 0) {
        const short* p = xP + (size_t)t * 8192 + aOff;   // static input, plain loads
        v8s afr[8];
#pragma unroll
        for (int kk = 0; kk < 8; ++kk) afr[kk] = *(const v8s*)(p + kk * 512);
        mfma32(afr, wfr, acc);
      } else {
        hp = h0 + (size_t)t * 8192 + aOff;               // layer-0 output, step t
      }
    } else if (t > 0) {
      hp = hOwn + (size_t)(t - 1) * 8192 + aOff;         // own recurrence, step t-1
    }

    if (hp) {
      v8s afr[8];
      unsigned mx = coh_load8(hp, afr);
      mfma32(afr, wfr, acc);                             // speculative; verify overlaps
      if (__ballot(mx == SENT) != 0) {                   // data not yet landed: retry
        do {
          __builtin_amdgcn_s_sleep(1);
          mx = coh_load8(hp, afr);
        } while (__ballot(mx == SENT) != 0);
#pragma unroll
        for (int nt = 0; nt < 4; ++nt) acc[nt] = (v4f){0.f, 0.f, 0.f, 0.f};
        mfma32(afr, wfr, acc);
      }
    }

#pragma unroll
    for (int nt = 0; nt < 4; ++nt) {
      const int rb = quad * 4;
#pragma unroll
      for (int r = 0; r < 4; ++r)
        LDSG[buf][wave][rb + r][nt * 16 + n15] = acc[nt][r];
    }
    __syncthreads();   // single barrier per step (LDSG double-buffered)

    // ---------- epilogue on waves 0+1: gates -> (c,h), fire-and-forget publish ----------
    if (wave < 2) {
      float2 s[4];
#pragma unroll
      for (int q = 0; q < 4; ++q) {
        const int coff = (hi * 2 + (q >> 1)) * 16 + (q & 1) * 8 + jj;
        float2 a0 = *(const float2*)&LDSG[buf][0][bb][coff];
        float2 a1 = *(const float2*)&LDSG[buf][1][bb][coff];
        float2 a2 = *(const float2*)&LDSG[buf][2][bb][coff];
        float2 a3 = *(const float2*)&LDSG[buf][3][bb][coff];
        s[q].x = a0.x + a1.x + a2.x + a3.x + bq[q][0];
        s[q].y = a0.y + a1.y + a2.y + a3.y + bq[q][1];
      }
      float i0 = sigmoid_fast(s[0].x), i1 = sigmoid_fast(s[0].y);
      float f0 = sigmoid_fast(s[1].x), f1 = sigmoid_fast(s[1].y);
      float g0 = tanh_fast(s[2].x),    g1 = tanh_fast(s[2].y);
      float o0 = sigmoid_fast(s[3].x), o1 = sigmoid_fast(s[3].y);
      c0 = f0 * c0 + i0 * g0;
      c1 = f1 * c1 + i1 * g1;
      float h0v = o0 * tanh_fast(c0);
      float h1v = o1 * tanh_fast(c1);
      unsigned pack = (unsigned)(unsigned short)f2bf(h0v) |
                      ((unsigned)(unsigned short)f2bf(h1v) << 16);
      // |h|<=1 so pack never equals SENT; single atomic u32 store IS the handoff.
      cohStoreU((unsigned*)hOwn + (size_t)t * 4096 + (2 * g + hi) * 64 + bb * 4 + (jp & 3), pack);
      if (l == 1) {
        float2 ov; ov.x = h0v + xv.x; ov.y = h1v + xv.y;
        *(float2*)(out + xi) = ov;
      }
    }
  }
}

extern "C" void kernel_launch(void* const* d_in, const int* in_sizes, int n_in,
                              void* d_out, int out_size, void* d_ws, size_t ws_size,
                              hipStream_t stream) {
  const float* x    = (const float*)d_in[0];
  const float* Wx   = (const float*)d_in[1];
  const float* Wh   = (const float*)d_in[2];
  const float* bias = (const float*)d_in[3];
  float* out = (float*)d_out;

  char* ws   = (char*)d_ws;
  short* wT  = (short*)(ws + WT_OFF);
  short* h0  = (short*)(ws + H0_OFF);
  short* h1  = (short*)(ws + H1_OFF);
  short* xP  = (short*)(ws + XB_OFF);
  unsigned* hwords = (unsigned*)(ws + H0_OFF);   // h0+h1 contiguous, 2^24 words

  hipLaunchKernelGGL(prep_weights, dim3(16384), dim3(256), 0, stream, Wx, Wh, wT);
  hipLaunchKernelGGL(prep_x, dim3(65536), dim3(256), 0, stream, x, xP, hwords);
  hipLaunchKernelGGL(lstm_persist, dim3(64), dim3(256), 0, stream,
                     x, xP, wT, bias, h0, h1, out);
}